// Round 11
// baseline (225.265 us; speedup 1.0000x reference)
//
#include <hip/hip_runtime.h>
#include <cstdint>

typedef unsigned short u16;
typedef __bf16 bf16x8 __attribute__((ext_vector_type(8)));
typedef float f32x4 __attribute__((ext_vector_type(4)));

// ---------- bf16 helpers (RNE) ----------
__device__ __forceinline__ u16 f2bf(float f) {
    unsigned u = __float_as_uint(f);
    u += 0x7fffu + ((u >> 16) & 1u);
    return (u16)(u >> 16);
}
__device__ __forceinline__ float bf2f(u16 h) {
    return __uint_as_float(((unsigned)h) << 16);
}

// ---------- async global->LDS (16B per lane, wave-uniform LDS base) ----------
__device__ __forceinline__ void lds16(const void* g, void* l) {
    __builtin_amdgcn_global_load_lds(
        (const __attribute__((address_space(1))) void*)g,
        (__attribute__((address_space(3))) void*)l, 16, 0, 0);
}

// ---------- positional encoding term for element e of row l ----------
__device__ __forceinline__ float pos_term(int l, int e) {
    const float c = -13.287712379549449f / 512.0f;       // -log2(10000)/512
    int ii = e & 511;
    float st  = exp2f(c * (float)ii);
    float arg = (float)l * st;
    return (e < 512) ? sinf(arg) : cosf(arg);
}

// ========== merged prep ==========
// blocks [0,4096):   x 64x32 tiles -> x_bf (row-major) AND xT (transposed, [1024][8192])
// blocks [4096,8192): weights -> bf16: mat0 = Wq, mat1 = Wk^T, mat2 = Wv^T, mat3 = Wl
__global__ __launch_bounds__(256) void prep_all(const float* __restrict__ seq,
                                                const float* __restrict__ wq,
                                                const float* __restrict__ wk,
                                                const float* __restrict__ wv,
                                                const float* __restrict__ wl,
                                                u16* __restrict__ xb,
                                                u16* __restrict__ xt,
                                                u16* __restrict__ wt) {
    const int bx = blockIdx.x;
    const int t = threadIdx.x;
    if (bx < 4096) {
        __shared__ u16 tb[64][33];
        const int rt = bx >> 5, ct = bx & 31;            // 128 row-tiles x 32 col-tiles
        const int r0 = rt * 64, c0 = ct * 32;
        const int r_l = t >> 2, c8 = (t & 3) * 8;        // load: 64 rows x 4 col-chunks
        const int row = r0 + r_l, l = row & 2047;
        const float* sp = seq + (size_t)row * 1024 + c0 + c8;
        float4 a0 = ((const float4*)sp)[0];
        float4 a1 = ((const float4*)sp)[1];
        float v[8] = {a0.x, a0.y, a0.z, a0.w, a1.x, a1.y, a1.z, a1.w};
        u16 ob[8];
#pragma unroll
        for (int jj = 0; jj < 8; jj++) {
            v[jj] += pos_term(l, c0 + c8 + jj);
            ob[jj] = f2bf(v[jj]);
            tb[r_l][c8 + jj] = ob[jj];
        }
        u16* xp = xb + (size_t)row * 1024 + c0 + c8;
        ((ushort4*)xp)[0] = *(const ushort4*)&ob[0];
        ((ushort4*)xp)[1] = *(const ushort4*)&ob[4];
        __syncthreads();
        const int c_l = t >> 3, r8 = (t & 7) * 8;        // store: 32 cols x 8 row-chunks
        u16 tv[8];
#pragma unroll
        for (int jj = 0; jj < 8; jj++) tv[jj] = tb[r8 + jj][c_l];
        u16* tp = xt + (size_t)(c0 + c_l) * 8192 + r0 + r8;
        ((ushort4*)tp)[0] = *(const ushort4*)&tv[0];
        ((ushort4*)tp)[1] = *(const ushort4*)&tv[4];
        return;
    }
    const int idx = bx - 4096;               // [0, 4096)
    const int mat = idx >> 10, bxw = idx & 1023;
    const int gx = bxw & 31, gy = bxw >> 5;
    const int tx = t & 31, ty = t >> 5;
    const float* src = (mat == 0) ? wq : (mat == 1) ? wk : (mat == 2) ? wv : wl;
    u16* dst = wt + (size_t)mat * 1024 * 1024;
    if (mat == 0 || mat == 3) {
        int col = gx * 32 + tx, row0 = gy * 32;
#pragma unroll
        for (int j = 0; j < 32; j += 8)
            dst[(size_t)(row0 + ty + j) * 1024 + col] = f2bf(src[(size_t)(row0 + ty + j) * 1024 + col]);
    } else {
        __shared__ float tile[32][33];
        int col = gx * 32 + tx, row0 = gy * 32;
#pragma unroll
        for (int j = 0; j < 32; j += 8)
            tile[ty + j][tx] = src[(size_t)(row0 + ty + j) * 1024 + col];
        __syncthreads();
        int col2 = gy * 32 + tx, row20 = gx * 32;
#pragma unroll
        for (int j = 0; j < 32; j += 8)
            dst[(size_t)(row20 + ty + j) * 1024 + col2] = f2bf(tile[tx][ty + j]);
    }
}

// ======== Gram: G_b = X_b^T X_b, 128x128 tiles, K=2048, batched (4 x 64 tiles) ========
// A = Bt = xT + b*2048 (xT is [1024][8192]); C_b = G + b*2^20, bf16 [1024][1024].
// Same proven 2-barrier counted-vmcnt structure + swizzle as gemm128 (0 conflicts R3-R10).
__global__ __launch_bounds__(256) void gram_kernel(const u16* __restrict__ xt,
                                                   u16* __restrict__ G) {
    __shared__ __align__(16) u16 lds[32768];   // 64 KB
    const int t = threadIdx.x;
    const int nwg = gridDim.x;                 // 256, %8==0
    int bid = (int)blockIdx.x;
    bid = (bid & 7) * (nwg >> 3) + (bid >> 3); // bijective XCD swizzle
    const int bt = bid >> 6, tile6 = bid & 63;
    const int tm = tile6 >> 3, tn = tile6 & 7;
    const size_t m0 = (size_t)tm << 7, n0 = (size_t)tn << 7;
    const int w = t >> 6, lane = t & 63;
    const int wr = w >> 1, wc = w & 1;
    const size_t lda = 8192;
    const u16* A = xt + (size_t)bt * 2048;

    const int r0 = t >> 3;                      // 0..31
    const int ksrc = (t & 7) ^ (r0 & 7);
    const u16* sA = A + (m0 + r0) * lda + ksrc * 8;
    const u16* sB = A + (n0 + r0) * lda + ksrc * 8;
    const size_t st = (size_t)32 * lda;

    const int kx = lane & 7;
    const int ks0 = (((lane >> 4) ^ kx) << 3);
    const int ks1 = (((4 + (lane >> 4)) ^ kx) << 3);
    const int ao = ((wr << 6) | (lane & 15)) << 6;
    const int bo = 8192 + ((((wc << 6) | (lane & 15))) << 6);

    f32x4 acc[4][4];
#pragma unroll
    for (int i = 0; i < 4; i++)
#pragma unroll
        for (int j = 0; j < 4; j++)
#pragma unroll
            for (int r = 0; r < 4; r++) acc[i][j][r] = 0.0f;

#define STAGEG(bb, ko)                                                        \
    do {                                                                      \
        u16* dA_ = lds + (bb) * 16384 + (w << 9);                             \
        u16* dB_ = dA_ + 8192;                                                \
        _Pragma("unroll")                                                     \
        for (int j_ = 0; j_ < 4; j_++) {                                      \
            lds16(sA + (ko) + j_ * st, dA_ + j_ * 2048);                      \
            lds16(sB + (ko) + j_ * st, dB_ + j_ * 2048);                      \
        }                                                                     \
    } while (0)

    const int NT = 32;                          // K = 2048
    STAGEG(0, 0);
    for (int kt = 0; kt < NT; kt++) {
        const int b = kt & 1;
        asm volatile("" ::: "memory");
        if (kt + 1 < NT) {
            STAGEG(b ^ 1, (size_t)(kt + 1) << 6);
            asm volatile("s_waitcnt vmcnt(8)" ::: "memory");
        } else {
            asm volatile("s_waitcnt vmcnt(0)" ::: "memory");
        }
        __builtin_amdgcn_s_barrier();
        asm volatile("" ::: "memory");
        const u16* Lb = lds + b * 16384;
#pragma unroll
        for (int kc = 0; kc < 2; kc++) {
            const int ksl = kc ? ks1 : ks0;
            bf16x8 af[4], bfr[4];
#pragma unroll
            for (int i = 0; i < 4; i++)
                af[i] = *reinterpret_cast<const bf16x8*>(Lb + ao + i * 1024 + ksl);
#pragma unroll
            for (int j = 0; j < 4; j++)
                bfr[j] = *reinterpret_cast<const bf16x8*>(Lb + bo + j * 1024 + ksl);
            __builtin_amdgcn_s_setprio(1);
#pragma unroll
            for (int i = 0; i < 4; i++)
#pragma unroll
                for (int j = 0; j < 4; j++)
                    acc[i][j] = __builtin_amdgcn_mfma_f32_16x16x32_bf16(af[i], bfr[j], acc[i][j], 0, 0, 0);
            __builtin_amdgcn_s_setprio(0);
        }
        asm volatile("" ::: "memory");
        __builtin_amdgcn_s_barrier();
    }
#undef STAGEG

    u16* C = G + ((size_t)bt << 20);
    const int crow = (lane >> 4) << 2, ccol = lane & 15;
#pragma unroll
    for (int i = 0; i < 4; i++)
#pragma unroll
        for (int j = 0; j < 4; j++) {
            size_t row = m0 + (wr << 6) + (i << 4) + crow;
            size_t col = n0 + (wc << 6) + (j << 4) + ccol;
#pragma unroll
            for (int r = 0; r < 4; r++)
                C[(row + r) * 1024 + col] = f2bf(acc[i][j][r]);
        }
}

// ============ 128x256 bf16 GEMM (2-barrier, counted vmcnt) — proven structure ============
// EPI: 2 = bf16 out, 3 = bf16 bias+relu out.
// bstride: if nonzero, Bt batched per 2048 A-rows.
template <int EPI>
__global__ __launch_bounds__(512) void gemm8p(const u16* __restrict__ A,
                                              const u16* __restrict__ Bt,
                                              void* __restrict__ Cv,
                                              const float* __restrict__ bias,
                                              int N, int K, int lda, size_t bstride) {
    __shared__ __align__(16) u16 lds[49152];   // 96 KB
    const int t = threadIdx.x;
    const int ntn = N >> 8;
    const int nwg = gridDim.x;                 // % 8 == 0
    int bid = (int)blockIdx.x;
    bid = (bid & 7) * (nwg >> 3) + (bid >> 3);
    const int tm = bid / ntn, tn = bid - tm * ntn;
    const size_t m0 = (size_t)tm << 7, n0 = (size_t)tn << 8;
    const int w = t >> 6, lane = t & 63;
    const int wr = w >> 2, wc = w & 3;
    const u16* Bt_e = Bt + (bstride ? (m0 >> 11) * bstride : 0);

    const int r0 = t >> 3;
    const int ksrc = (t & 7) ^ (r0 & 7);
    const u16* sA0 = A + (m0 + r0) * (size_t)lda + ksrc * 8;
    const u16* sA1 = sA0 + (size_t)64 * lda;
    const u16* sB0 = Bt_e + (n0 + r0) * (size_t)K + ksrc * 8;
    const u16* sB1 = sB0 + (size_t)64 * K;
    const u16* sB2 = sB0 + (size_t)128 * K;
    const u16* sB3 = sB0 + (size_t)192 * K;
    u16* dstW = lds + (w << 9);

    const int ao = ((wr << 6) | (lane & 15)) << 6;
    const int bo = 8192 + ((((wc << 6) | (lane & 15))) << 6);
    const int kx = lane & 7;
    const int ks0 = (((lane >> 4) ^ kx) << 3);
    const int ks1 = (((4 + (lane >> 4)) ^ kx) << 3);

    f32x4 acc[4][4];
#pragma unroll
    for (int i = 0; i < 4; i++)
#pragma unroll
        for (int j = 0; j < 4; j++)
#pragma unroll
            for (int r = 0; r < 4; r++) acc[i][j][r] = 0.0f;

    const int NT = K >> 6;
    lds16(sA0, dstW);          lds16(sA1, dstW + 4096);
    lds16(sB0, dstW + 8192);   lds16(sB1, dstW + 12288);
    lds16(sB2, dstW + 16384);  lds16(sB3, dstW + 20480);

    for (int kt = 0; kt < NT; kt++) {
        const int b = kt & 1;
        asm volatile("" ::: "memory");
        if (kt + 1 < NT) {
            const size_t ko = (size_t)(kt + 1) << 6;
            u16* d = dstW + (b ^ 1) * 24576;
            lds16(sA0 + ko, d);          lds16(sA1 + ko, d + 4096);
            lds16(sB0 + ko, d + 8192);   lds16(sB1 + ko, d + 12288);
            lds16(sB2 + ko, d + 16384);  lds16(sB3 + ko, d + 20480);
            asm volatile("s_waitcnt vmcnt(6)" ::: "memory");
        } else {
            asm volatile("s_waitcnt vmcnt(0)" ::: "memory");
        }
        __builtin_amdgcn_s_barrier();
        asm volatile("" ::: "memory");
        const u16* Lb = lds + b * 24576;
#pragma unroll
        for (int kc = 0; kc < 2; kc++) {
            const int ksl = kc ? ks1 : ks0;
            bf16x8 af[4], bfr[4];
#pragma unroll
            for (int i = 0; i < 4; i++)
                af[i] = *reinterpret_cast<const bf16x8*>(Lb + ao + i * 1024 + ksl);
#pragma unroll
            for (int j = 0; j < 4; j++)
                bfr[j] = *reinterpret_cast<const bf16x8*>(Lb + bo + j * 1024 + ksl);
            __builtin_amdgcn_s_setprio(1);
#pragma unroll
            for (int i = 0; i < 4; i++)
#pragma unroll
                for (int j = 0; j < 4; j++)
                    acc[i][j] = __builtin_amdgcn_mfma_f32_16x16x32_bf16(af[i], bfr[j], acc[i][j], 0, 0, 0);
            __builtin_amdgcn_s_setprio(0);
        }
        asm volatile("" ::: "memory");
        __builtin_amdgcn_s_barrier();
    }

    const int crow = (lane >> 4) << 2, ccol = lane & 15;
#pragma unroll
    for (int i = 0; i < 4; i++)
#pragma unroll
        for (int j = 0; j < 4; j++) {
            size_t row = m0 + (wr << 6) + (i << 4) + crow;
            size_t col = n0 + (wc << 6) + (j << 4) + ccol;
#pragma unroll
            for (int r = 0; r < 4; r++) {
                float v = acc[i][j][r];
                if (EPI == 3) { v += bias[col]; v = fmaxf(v, 0.0f); }
                ((u16*)Cv)[(row + r) * (size_t)N + col] = f2bf(v);
            }
        }
}

// ============ 128x128 bf16 GEMM (2-barrier, counted vmcnt) — full-machine small GEMMs ============
// ADDI: add identity (C[row][col] += (col == row&1023)) for the Wcomb fold.
template <bool ADDI>
__global__ __launch_bounds__(256) void gemm128(const u16* __restrict__ A,
                                               const u16* __restrict__ Bt,
                                               u16* __restrict__ C,
                                               int N, int K, int lda) {
    __shared__ __align__(16) u16 lds[32768];   // 64 KB
    const int t = threadIdx.x;
    const int ntn = N >> 7;
    const int nwg = gridDim.x;                 // % 8 == 0
    int bid = (int)blockIdx.x;
    bid = (bid & 7) * (nwg >> 3) + (bid >> 3);
    const int tm = bid / ntn, tn = bid - tm * ntn;
    const size_t m0 = (size_t)tm << 7, n0 = (size_t)tn << 7;
    const int w = t >> 6, lane = t & 63;
    const int wr = w >> 1, wc = w & 1;

    const int r0 = t >> 3;                      // 0..31
    const int ksrc = (t & 7) ^ (r0 & 7);
    const u16* sA = A + (m0 + r0) * (size_t)lda + ksrc * 8;
    const u16* sB = Bt + (n0 + r0) * (size_t)K + ksrc * 8;
    const size_t stA = (size_t)32 * lda, stB = (size_t)32 * K;

    const int kx = lane & 7;
    const int ks0 = (((lane >> 4) ^ kx) << 3);
    const int ks1 = (((4 + (lane >> 4)) ^ kx) << 3);
    const int ao = ((wr << 6) | (lane & 15)) << 6;
    const int bo = 8192 + ((((wc << 6) | (lane & 15))) << 6);

    f32x4 acc[4][4];
#pragma unroll
    for (int i = 0; i < 4; i++)
#pragma unroll
        for (int j = 0; j < 4; j++)
#pragma unroll
            for (int r = 0; r < 4; r++) acc[i][j][r] = 0.0f;

#define STAGE128(bb, ko)                                                      \
    do {                                                                      \
        u16* dA_ = lds + (bb) * 16384 + (w << 9);                             \
        u16* dB_ = dA_ + 8192;                                                \
        _Pragma("unroll")                                                     \
        for (int j_ = 0; j_ < 4; j_++) {                                      \
            lds16(sA + (ko) + j_ * stA, dA_ + j_ * 2048);                     \
            lds16(sB + (ko) + j_ * stB, dB_ + j_ * 2048);                     \
        }                                                                     \
    } while (0)

    const int NT = K >> 6;
    STAGE128(0, 0);
    for (int kt = 0; kt < NT; kt++) {
        const int b = kt & 1;
        asm volatile("" ::: "memory");
        if (kt + 1 < NT) {
            STAGE128(b ^ 1, (size_t)(kt + 1) << 6);
            asm volatile("s_waitcnt vmcnt(8)" ::: "memory");
        } else {
            asm volatile("s_waitcnt vmcnt(0)" ::: "memory");
        }
        __builtin_amdgcn_s_barrier();
        asm volatile("" ::: "memory");
        const u16* Lb = lds + b * 16384;
#pragma unroll
        for (int kc = 0; kc < 2; kc++) {
            const int ksl = kc ? ks1 : ks0;
            bf16x8 af[4], bfr[4];
#pragma unroll
            for (int i = 0; i < 4; i++)
                af[i] = *reinterpret_cast<const bf16x8*>(Lb + ao + i * 1024 + ksl);
#pragma unroll
            for (int j = 0; j < 4; j++)
                bfr[j] = *reinterpret_cast<const bf16x8*>(Lb + bo + j * 1024 + ksl);
            __builtin_amdgcn_s_setprio(1);
#pragma unroll
            for (int i = 0; i < 4; i++)
#pragma unroll
                for (int j = 0; j < 4; j++)
                    acc[i][j] = __builtin_amdgcn_mfma_f32_16x16x32_bf16(af[i], bfr[j], acc[i][j], 0, 0, 0);
            __builtin_amdgcn_s_setprio(0);
        }
        asm volatile("" ::: "memory");
        __builtin_amdgcn_s_barrier();
    }
#undef STAGE128

    const int crow = (lane >> 4) << 2, ccol = lane & 15;
#pragma unroll
    for (int i = 0; i < 4; i++)
#pragma unroll
        for (int j = 0; j < 4; j++) {
            size_t row = m0 + (wr << 6) + (i << 4) + crow;
            size_t col = n0 + (wc << 6) + (j << 4) + ccol;
#pragma unroll
            for (int r = 0; r < 4; r++) {
                float v = acc[i][j][r];
                if (ADDI && col == ((row + r) & 1023)) v += 1.0f;
                C[(row + r) * (size_t)N + col] = f2bf(v);
            }
        }
}

// ===== KtV_bh[i][j] = sum_d WkT[h*64+i][d] * T_b[d][h*64+j]  -> f32 ktv =====
// grid (64 bh, 4 ig); 256 threads = 4 waves, each wave owns a d-quarter (wave-uniform
// via readfirstlane -> WkT reads go down the scalar path and dual-issue with VALU).
__global__ __launch_bounds__(256) void ktv_small(const u16* __restrict__ T,
                                                 const u16* __restrict__ WkT,
                                                 float* __restrict__ ktv) {
    const int bh = blockIdx.x, ig = blockIdx.y;
    const int b = bh >> 4, h = bh & 15;
    const int t = threadIdx.x;
    const int j = t & 63;
    const int dq = __builtin_amdgcn_readfirstlane(t >> 6);   // wave-uniform d-quarter
    const u16* Tb = T + ((size_t)b * 1024) * 1024 + h * 64;  // + d*1024 + j
    const u16* Wk = WkT + (size_t)(h * 64 + ig * 16) * 1024; // + i*1024 + d
    float acc[16];
#pragma unroll
    for (int i = 0; i < 16; i++) acc[i] = 0.0f;
    const int d0 = dq * 256;
    for (int d = d0; d < d0 + 256; d += 2) {
        float tv0 = bf2f(Tb[(size_t)d * 1024 + j]);
        float tv1 = bf2f(Tb[(size_t)(d + 1) * 1024 + j]);
#pragma unroll
        for (int i = 0; i < 16; i++) {
            unsigned wv = *(const unsigned*)(Wk + i * 1024 + d);  // wave-uniform -> s_load
            acc[i] += bf2f((u16)wv) * tv0 + bf2f((u16)(wv >> 16)) * tv1;
        }
    }
    __shared__ float red[4][16][64];   // 16 KB
#pragma unroll
    for (int i = 0; i < 16; i++) red[t >> 6][i][j] = acc[i];
    __syncthreads();
    if (t < 64) {
#pragma unroll
        for (int i = 0; i < 16; i++) {
            float s = red[0][i][j] + red[1][i][j] + red[2][i][j] + red[3][i][j];
            ktv[((size_t)bh << 12) + (ig * 16 + i) * 64 + j] = s;
        }
    }
}

// ===== W'^T_b[n][h*64+i] = sum_j (KtV_bh[i][j]/8) * Wo[h*64+j][n]  -> bf16 =====
// kt reads are wave-uniform GLOBAL addresses -> s_load (K$ path), dual-issues with VALU.
__global__ __launch_bounds__(256) void wprime_kernel(const float* __restrict__ ktv,
                                                     const float* __restrict__ Wo,
                                                     u16* __restrict__ wp) {
    const int n = blockIdx.x * 256 + threadIdx.x;   // blockIdx.x in [0,4)
    const int h = blockIdx.y, b = blockIdx.z;
    const float* kt = ktv + ((size_t)(b * 16 + h) << 12);
    float acc[64];
#pragma unroll
    for (int i = 0; i < 64; i++) acc[i] = 0.0f;
    for (int j = 0; j < 64; j++) {
        float w = Wo[(size_t)(h * 64 + j) * 1024 + n];
#pragma unroll
        for (int i = 0; i < 64; i++) acc[i] += kt[i * 64 + j] * w;
    }
    u16* o = wp + ((size_t)b << 20) + (size_t)n * 1024 + h * 64;
    u16 ob[64];
#pragma unroll
    for (int i = 0; i < 64; i++) ob[i] = f2bf(acc[i] * 0.125f);
#pragma unroll
    for (int i = 0; i < 8; i++)
        ((uint4*)o)[i] = ((const uint4*)ob)[i];
}

// ===== LN1: h1b = bf16(LN(xr)) — xr already holds x + attn_out (identity fold) =====
__global__ __launch_bounds__(256) void ln1_kernel(const u16* __restrict__ xr,
                                                  const float* __restrict__ g,
                                                  const float* __restrict__ be,
                                                  u16* __restrict__ outB) {
    __shared__ float sm[4];
    const int row = blockIdx.x, t = threadIdx.x;
    const ushort4 xv = ((const ushort4*)(xr + (size_t)row * 1024))[t];
    float x0 = bf2f(xv.x), x1 = bf2f(xv.y), x2 = bf2f(xv.z), x3 = bf2f(xv.w);
    float s = x0 + x1 + x2 + x3;
#pragma unroll
    for (int off = 32; off > 0; off >>= 1) s += __shfl_down(s, off);
    if ((t & 63) == 0) sm[t >> 6] = s;
    __syncthreads();
    const float mean = (sm[0] + sm[1] + sm[2] + sm[3]) * (1.0f / 1024.0f);
    __syncthreads();
    x0 -= mean; x1 -= mean; x2 -= mean; x3 -= mean;
    float s2 = x0 * x0 + x1 * x1 + x2 * x2 + x3 * x3;
#pragma unroll
    for (int off = 32; off > 0; off >>= 1) s2 += __shfl_down(s2, off);
    if ((t & 63) == 0) sm[t >> 6] = s2;
    __syncthreads();
    const float var = (sm[0] + sm[1] + sm[2] + sm[3]) * (1.0f / 1024.0f);
    const float rs = rsqrtf(var + 1e-5f);
    const float4 gv = ((const float4*)g)[t];
    const float4 bv = ((const float4*)be)[t];
    ushort4 ob;
    ob.x = f2bf(x0 * rs * gv.x + bv.x);
    ob.y = f2bf(x1 * rs * gv.y + bv.y);
    ob.z = f2bf(x2 * rs * gv.z + bv.z);
    ob.w = f2bf(x3 * rs * gv.w + bv.w);
    ((ushort4*)(outB + (size_t)row * 1024))[t] = ob;
}

// ===== LN2: out = f32(LN(ff_bf + h1_bf)) =====
__global__ __launch_bounds__(256) void ln2_kernel(const u16* __restrict__ ff,
                                                  const u16* __restrict__ h1,
                                                  const float* __restrict__ g,
                                                  const float* __restrict__ be,
                                                  float* __restrict__ outF) {
    __shared__ float sm[4];
    const int row = blockIdx.x, t = threadIdx.x;
    const ushort4 fv = ((const ushort4*)(ff + (size_t)row * 1024))[t];
    const ushort4 hv = ((const ushort4*)(h1 + (size_t)row * 1024))[t];
    float x0 = bf2f(fv.x) + bf2f(hv.x), x1 = bf2f(fv.y) + bf2f(hv.y);
    float x2 = bf2f(fv.z) + bf2f(hv.z), x3 = bf2f(fv.w) + bf2f(hv.w);
    float s = x0 + x1 + x2 + x3;
#pragma unroll
    for (int off = 32; off > 0; off >>= 1) s += __shfl_down(s, off);
    if ((t & 63) == 0) sm[t >> 6] = s;
    __syncthreads();
    const float mean = (sm[0] + sm[1] + sm[2] + sm[3]) * (1.0f / 1024.0f);
    __syncthreads();
    x0 -= mean; x1 -= mean; x2 -= mean; x3 -= mean;
    float s2 = x0 * x0 + x1 * x1 + x2 * x2 + x3 * x3;
#pragma unroll
    for (int off = 32; off > 0; off >>= 1) s2 += __shfl_down(s2, off);
    if ((t & 63) == 0) sm[t >> 6] = s2;
    __syncthreads();
    const float var = (sm[0] + sm[1] + sm[2] + sm[3]) * (1.0f / 1024.0f);
    const float rs = rsqrtf(var + 1e-5f);
    const float4 gv = ((const float4*)g)[t];
    const float4 bv = ((const float4*)be)[t];
    float4 o;
    o.x = x0 * rs * gv.x + bv.x;
    o.y = x1 * rs * gv.y + bv.y;
    o.z = x2 * rs * gv.z + bv.z;
    o.w = x3 * rs * gv.w + bv.w;
    ((float4*)(outF + (size_t)row * 1024))[t] = o;
}

extern "C" void kernel_launch(void* const* d_in, const int* in_sizes, int n_in,
                              void* d_out, int out_size, void* d_ws, size_t ws_size,
                              hipStream_t stream) {
    const float* seq = (const float*)d_in[0];
    const float* Wq  = (const float*)d_in[1];
    const float* Wk  = (const float*)d_in[2];
    const float* Wv  = (const float*)d_in[3];
    const float* Wo  = (const float*)d_in[4];
    const float* g1  = (const float*)d_in[5];
    const float* b1  = (const float*)d_in[6];
    const float* Wl  = (const float*)d_in[7];
    const float* bl  = (const float*)d_in[8];
    const float* g2  = (const float*)d_in[9];
    const float* b2  = (const float*)d_in[10];

    char* ws = (char*)d_ws;
    const size_t MB = 1024 * 1024;
    u16*   x_bf    = (u16*)(ws + 0);            // 16 MB [8192][1024]
    u16*   wt      = (u16*)(ws + 16 * MB);      // 8 MB: [Wq, Wk^T, Wv^T, Wl] bf16
    u16*   xT      = (u16*)(ws + 24 * MB);      // 16 MB [1024][8192] (x transposed)
    u16*   G       = (u16*)(ws + 40 * MB);      // 8 MB  [4][1024][1024] Gram per batch
    u16*   Tm      = (u16*)(ws + 48 * MB);      // 8 MB  [4096][1024] T = G @ Wv
    float* ktv     = (float*)(ws + 56 * MB);    // 1 MB  [64][64][64]
    u16*   wpr     = (u16*)(ws + 57 * MB);      // 8 MB  [4][1024][1024] W'^T per batch
    u16*   wcomb   = (u16*)(ws + 65 * MB);      // 8 MB  [4][1024][1024] (I + Wcomb)^T per batch
    u16*   attnres = (u16*)(ws + 73 * MB);      // 16 MB — holds x + attn_out
    u16*   h1b     = (u16*)(ws + 89 * MB);      // 16 MB
    u16*   ffb     = (u16*)(ws + 105 * MB);     // 16 MB

    // 1. x_bf + xT = bf16(seq + positional) (both layouts); weights -> bf16  (merged)
    prep_all<<<dim3(4096 + 4096), dim3(256), 0, stream>>>(seq, Wq, Wk, Wv, Wl,
                                                          x_bf, xT, wt);
    // 2. G_b = X_b^T X_b  (K=2048; grid 4 batches x 64 tiles = 256)
    gram_kernel<<<dim3(256), dim3(256), 0, stream>>>(xT, G);
    // 3. T = G_stack @ Wv  ([4096,1024] @ [1024,1024]; grid 32x8 = 256)
    gemm128<false><<<dim3(256), dim3(256), 0, stream>>>(G, wt + (size_t)2 * MB, Tm,
                                                        1024, 1024, 1024);
    // 4. KtV_bh = Wk_h^T T_b[:,h]  -> f32 ktv  (grid 64 x 4)
    ktv_small<<<dim3(64, 4), dim3(256), 0, stream>>>(Tm, wt + (size_t)1 * MB, ktv);
    // 5. W'^T_b = (blockdiag(KtV_b)/8 @ Wo)^T -> bf16  (kt via scalar-load path)
    wprime_kernel<<<dim3(4, 16, 4), dim3(256), 0, stream>>>(ktv, Wo, wpr);
    // 6. (I + Wcomb)^T_b = W'^T_b @ Wq^T + I  (grid 32x8 = 256)
    gemm128<true><<<dim3(256), dim3(256), 0, stream>>>(wpr, wt, wcomb, 1024, 1024, 1024);
    // 7. attnres = x @ (I + Wcomb_b) = x + attn_out  (B batched per 2048 rows; grid 256)
    gemm8p<2><<<dim3(256), dim3(512), 0, stream>>>(x_bf, wcomb, attnres, nullptr,
                                                   1024, 1024, 1024, (size_t)1024 * 1024);
    // 8. h1b = bf16(LN(attnres))
    ln1_kernel<<<dim3(8192), dim3(256), 0, stream>>>(attnres, g1, b1, h1b);
    // 9. ff = relu(h1 @ Wl^T + bl) -> bf16  (grid 256)
    gemm8p<3><<<dim3(256), dim3(512), 0, stream>>>(h1b, wt + (size_t)3 * MB, ffb,
                                                   bl, 1024, 1024, 1024, 0);
    // 10. out = LN(ff + h1)
    ln2_kernel<<<dim3(8192), dim3(256), 0, stream>>>(ffb, h1b, g2, b2, (float*)d_out);
}

// Round 12
// 186.440 us; speedup vs baseline: 1.2082x; 1.2082x over previous
//
#include <hip/hip_runtime.h>
#include <cstdint>

typedef unsigned short u16;
typedef __bf16 bf16x8 __attribute__((ext_vector_type(8)));
typedef float f32x4 __attribute__((ext_vector_type(4)));

// ---------- bf16 helpers (RNE) ----------
__device__ __forceinline__ u16 f2bf(float f) {
    unsigned u = __float_as_uint(f);
    u += 0x7fffu + ((u >> 16) & 1u);
    return (u16)(u >> 16);
}
__device__ __forceinline__ float bf2f(u16 h) {
    return __uint_as_float(((unsigned)h) << 16);
}

// ---------- async global->LDS (16B per lane, wave-uniform LDS base) ----------
__device__ __forceinline__ void lds16(const void* g, void* l) {
    __builtin_amdgcn_global_load_lds(
        (const __attribute__((address_space(1))) void*)g,
        (__attribute__((address_space(3))) void*)l, 16, 0, 0);
}

// ---------- positional encoding term for element e of row l ----------
__device__ __forceinline__ float pos_term(int l, int e) {
    const float c = -13.287712379549449f / 512.0f;       // -log2(10000)/512
    int ii = e & 511;
    float st  = exp2f(c * (float)ii);
    float arg = (float)l * st;
    return (e < 512) ? sinf(arg) : cosf(arg);
}

// ========== merged prep ==========
// blocks [0,4096):        x 64x32 tiles -> x_bf (row-major) AND xT ([1024][8192])
// blocks [4096,4096+5120): weights -> bf16: mat0=Wq, mat1=Wk^T, mat2=Wv^T, mat3=Wl, mat4=Wk
__global__ __launch_bounds__(256) void prep_all(const float* __restrict__ seq,
                                                const float* __restrict__ wq,
                                                const float* __restrict__ wk,
                                                const float* __restrict__ wv,
                                                const float* __restrict__ wl,
                                                u16* __restrict__ xb,
                                                u16* __restrict__ xt,
                                                u16* __restrict__ wt) {
    const int bx = blockIdx.x;
    const int t = threadIdx.x;
    if (bx < 4096) {
        __shared__ u16 tb[64][33];
        const int rt = bx >> 5, ct = bx & 31;            // 128 row-tiles x 32 col-tiles
        const int r0 = rt * 64, c0 = ct * 32;
        const int r_l = t >> 2, c8 = (t & 3) * 8;        // load: 64 rows x 4 col-chunks
        const int row = r0 + r_l, l = row & 2047;
        const float* sp = seq + (size_t)row * 1024 + c0 + c8;
        float4 a0 = ((const float4*)sp)[0];
        float4 a1 = ((const float4*)sp)[1];
        float v[8] = {a0.x, a0.y, a0.z, a0.w, a1.x, a1.y, a1.z, a1.w};
        u16 ob[8];
#pragma unroll
        for (int jj = 0; jj < 8; jj++) {
            v[jj] += pos_term(l, c0 + c8 + jj);
            ob[jj] = f2bf(v[jj]);
            tb[r_l][c8 + jj] = ob[jj];
        }
        u16* xp = xb + (size_t)row * 1024 + c0 + c8;
        ((ushort4*)xp)[0] = *(const ushort4*)&ob[0];
        ((ushort4*)xp)[1] = *(const ushort4*)&ob[4];
        __syncthreads();
        const int c_l = t >> 3, r8 = (t & 7) * 8;        // store: 32 cols x 8 row-chunks
        u16 tv[8];
#pragma unroll
        for (int jj = 0; jj < 8; jj++) tv[jj] = tb[r8 + jj][c_l];
        u16* tp = xt + (size_t)(c0 + c_l) * 8192 + r0 + r8;
        ((ushort4*)tp)[0] = *(const ushort4*)&tv[0];
        ((ushort4*)tp)[1] = *(const ushort4*)&tv[4];
        return;
    }
    const int idx = bx - 4096;               // [0, 5120)
    const int mat = idx >> 10, bxw = idx & 1023;
    const int gx = bxw & 31, gy = bxw >> 5;
    const int tx = t & 31, ty = t >> 5;
    const float* src = (mat == 0) ? wq : (mat == 1) ? wk : (mat == 2) ? wv
                     : (mat == 3) ? wl : wk;
    u16* dst = wt + (size_t)mat * 1024 * 1024;
    if (mat == 0 || mat == 3 || mat == 4) {
        int col = gx * 32 + tx, row0 = gy * 32;
#pragma unroll
        for (int j = 0; j < 32; j += 8)
            dst[(size_t)(row0 + ty + j) * 1024 + col] = f2bf(src[(size_t)(row0 + ty + j) * 1024 + col]);
    } else {
        __shared__ float tile[32][33];
        int col = gx * 32 + tx, row0 = gy * 32;
#pragma unroll
        for (int j = 0; j < 32; j += 8)
            tile[ty + j][tx] = src[(size_t)(row0 + ty + j) * 1024 + col];
        __syncthreads();
        int col2 = gy * 32 + tx, row20 = gx * 32;
#pragma unroll
        for (int j = 0; j < 32; j += 8)
            dst[(size_t)(row20 + ty + j) * 1024 + col2] = f2bf(tile[tx][ty + j]);
    }
}

// ======== Gram: G_b = X_b^T X_b, 128x128 tiles, K=2048, batched (4 x 64 tiles) ========
__global__ __launch_bounds__(256) void gram_kernel(const u16* __restrict__ xt,
                                                   u16* __restrict__ G) {
    __shared__ __align__(16) u16 lds[32768];   // 64 KB
    const int t = threadIdx.x;
    const int nwg = gridDim.x;                 // 256, %8==0
    int bid = (int)blockIdx.x;
    bid = (bid & 7) * (nwg >> 3) + (bid >> 3); // bijective XCD swizzle
    const int bt = bid >> 6, tile6 = bid & 63;
    const int tm = tile6 >> 3, tn = tile6 & 7;
    const size_t m0 = (size_t)tm << 7, n0 = (size_t)tn << 7;
    const int w = t >> 6, lane = t & 63;
    const int wr = w >> 1, wc = w & 1;
    const size_t lda = 8192;
    const u16* A = xt + (size_t)bt * 2048;

    const int r0 = t >> 3;                      // 0..31
    const int ksrc = (t & 7) ^ (r0 & 7);
    const u16* sA = A + (m0 + r0) * lda + ksrc * 8;
    const u16* sB = A + (n0 + r0) * lda + ksrc * 8;
    const size_t st = (size_t)32 * lda;

    const int kx = lane & 7;
    const int ks0 = (((lane >> 4) ^ kx) << 3);
    const int ks1 = (((4 + (lane >> 4)) ^ kx) << 3);
    const int ao = ((wr << 6) | (lane & 15)) << 6;
    const int bo = 8192 + ((((wc << 6) | (lane & 15))) << 6);

    f32x4 acc[4][4];
#pragma unroll
    for (int i = 0; i < 4; i++)
#pragma unroll
        for (int j = 0; j < 4; j++)
#pragma unroll
            for (int r = 0; r < 4; r++) acc[i][j][r] = 0.0f;

#define STAGEG(bb, ko)                                                        \
    do {                                                                      \
        u16* dA_ = lds + (bb) * 16384 + (w << 9);                             \
        u16* dB_ = dA_ + 8192;                                                \
        _Pragma("unroll")                                                     \
        for (int j_ = 0; j_ < 4; j_++) {                                      \
            lds16(sA + (ko) + j_ * st, dA_ + j_ * 2048);                      \
            lds16(sB + (ko) + j_ * st, dB_ + j_ * 2048);                      \
        }                                                                     \
    } while (0)

    const int NT = 32;                          // K = 2048
    STAGEG(0, 0);
    for (int kt = 0; kt < NT; kt++) {
        const int b = kt & 1;
        asm volatile("" ::: "memory");
        if (kt + 1 < NT) {
            STAGEG(b ^ 1, (size_t)(kt + 1) << 6);
            asm volatile("s_waitcnt vmcnt(8)" ::: "memory");
        } else {
            asm volatile("s_waitcnt vmcnt(0)" ::: "memory");
        }
        __builtin_amdgcn_s_barrier();
        asm volatile("" ::: "memory");
        const u16* Lb = lds + b * 16384;
#pragma unroll
        for (int kc = 0; kc < 2; kc++) {
            const int ksl = kc ? ks1 : ks0;
            bf16x8 af[4], bfr[4];
#pragma unroll
            for (int i = 0; i < 4; i++)
                af[i] = *reinterpret_cast<const bf16x8*>(Lb + ao + i * 1024 + ksl);
#pragma unroll
            for (int j = 0; j < 4; j++)
                bfr[j] = *reinterpret_cast<const bf16x8*>(Lb + bo + j * 1024 + ksl);
            __builtin_amdgcn_s_setprio(1);
#pragma unroll
            for (int i = 0; i < 4; i++)
#pragma unroll
                for (int j = 0; j < 4; j++)
                    acc[i][j] = __builtin_amdgcn_mfma_f32_16x16x32_bf16(af[i], bfr[j], acc[i][j], 0, 0, 0);
            __builtin_amdgcn_s_setprio(0);
        }
        asm volatile("" ::: "memory");
        __builtin_amdgcn_s_barrier();
    }
#undef STAGEG

    u16* C = G + ((size_t)bt << 20);
    const int crow = (lane >> 4) << 2, ccol = lane & 15;
#pragma unroll
    for (int i = 0; i < 4; i++)
#pragma unroll
        for (int j = 0; j < 4; j++) {
            size_t row = m0 + (wr << 6) + (i << 4) + crow;
            size_t col = n0 + (wc << 6) + (j << 4) + ccol;
#pragma unroll
            for (int r = 0; r < 4; r++)
                C[(row + r) * 1024 + col] = f2bf(acc[i][j][r]);
        }
}

// ============ 128x256 bf16 GEMM (2-barrier, counted vmcnt) — proven structure ============
// EPI: 2 = bf16 out, 3 = bf16 bias+relu out.
// bstride: if nonzero, Bt batched per 2048 A-rows.
template <int EPI>
__global__ __launch_bounds__(512) void gemm8p(const u16* __restrict__ A,
                                              const u16* __restrict__ Bt,
                                              void* __restrict__ Cv,
                                              const float* __restrict__ bias,
                                              int N, int K, int lda, size_t bstride) {
    __shared__ __align__(16) u16 lds[49152];   // 96 KB
    const int t = threadIdx.x;
    const int ntn = N >> 8;
    const int nwg = gridDim.x;                 // % 8 == 0
    int bid = (int)blockIdx.x;
    bid = (bid & 7) * (nwg >> 3) + (bid >> 3);
    const int tm = bid / ntn, tn = bid - tm * ntn;
    const size_t m0 = (size_t)tm << 7, n0 = (size_t)tn << 8;
    const int w = t >> 6, lane = t & 63;
    const int wr = w >> 2, wc = w & 3;
    const u16* Bt_e = Bt + (bstride ? (m0 >> 11) * bstride : 0);

    const int r0 = t >> 3;
    const int ksrc = (t & 7) ^ (r0 & 7);
    const u16* sA0 = A + (m0 + r0) * (size_t)lda + ksrc * 8;
    const u16* sA1 = sA0 + (size_t)64 * lda;
    const u16* sB0 = Bt_e + (n0 + r0) * (size_t)K + ksrc * 8;
    const u16* sB1 = sB0 + (size_t)64 * K;
    const u16* sB2 = sB0 + (size_t)128 * K;
    const u16* sB3 = sB0 + (size_t)192 * K;
    u16* dstW = lds + (w << 9);

    const int ao = ((wr << 6) | (lane & 15)) << 6;
    const int bo = 8192 + ((((wc << 6) | (lane & 15))) << 6);
    const int kx = lane & 7;
    const int ks0 = (((lane >> 4) ^ kx) << 3);
    const int ks1 = (((4 + (lane >> 4)) ^ kx) << 3);

    f32x4 acc[4][4];
#pragma unroll
    for (int i = 0; i < 4; i++)
#pragma unroll
        for (int j = 0; j < 4; j++)
#pragma unroll
            for (int r = 0; r < 4; r++) acc[i][j][r] = 0.0f;

    const int NT = K >> 6;
    lds16(sA0, dstW);          lds16(sA1, dstW + 4096);
    lds16(sB0, dstW + 8192);   lds16(sB1, dstW + 12288);
    lds16(sB2, dstW + 16384);  lds16(sB3, dstW + 20480);

    for (int kt = 0; kt < NT; kt++) {
        const int b = kt & 1;
        asm volatile("" ::: "memory");
        if (kt + 1 < NT) {
            const size_t ko = (size_t)(kt + 1) << 6;
            u16* d = dstW + (b ^ 1) * 24576;
            lds16(sA0 + ko, d);          lds16(sA1 + ko, d + 4096);
            lds16(sB0 + ko, d + 8192);   lds16(sB1 + ko, d + 12288);
            lds16(sB2 + ko, d + 16384);  lds16(sB3 + ko, d + 20480);
            asm volatile("s_waitcnt vmcnt(6)" ::: "memory");
        } else {
            asm volatile("s_waitcnt vmcnt(0)" ::: "memory");
        }
        __builtin_amdgcn_s_barrier();
        asm volatile("" ::: "memory");
        const u16* Lb = lds + b * 24576;
#pragma unroll
        for (int kc = 0; kc < 2; kc++) {
            const int ksl = kc ? ks1 : ks0;
            bf16x8 af[4], bfr[4];
#pragma unroll
            for (int i = 0; i < 4; i++)
                af[i] = *reinterpret_cast<const bf16x8*>(Lb + ao + i * 1024 + ksl);
#pragma unroll
            for (int j = 0; j < 4; j++)
                bfr[j] = *reinterpret_cast<const bf16x8*>(Lb + bo + j * 1024 + ksl);
            __builtin_amdgcn_s_setprio(1);
#pragma unroll
            for (int i = 0; i < 4; i++)
#pragma unroll
                for (int j = 0; j < 4; j++)
                    acc[i][j] = __builtin_amdgcn_mfma_f32_16x16x32_bf16(af[i], bfr[j], acc[i][j], 0, 0, 0);
            __builtin_amdgcn_s_setprio(0);
        }
        asm volatile("" ::: "memory");
        __builtin_amdgcn_s_barrier();
    }

    const int crow = (lane >> 4) << 2, ccol = lane & 15;
#pragma unroll
    for (int i = 0; i < 4; i++)
#pragma unroll
        for (int j = 0; j < 4; j++) {
            size_t row = m0 + (wr << 6) + (i << 4) + crow;
            size_t col = n0 + (wc << 6) + (j << 4) + ccol;
#pragma unroll
            for (int r = 0; r < 4; r++) {
                float v = acc[i][j][r];
                if (EPI == 3) { v += bias[col]; v = fmaxf(v, 0.0f); }
                ((u16*)Cv)[(row + r) * (size_t)N + col] = f2bf(v);
            }
        }
}

// ============ 128x128 bf16 GEMM (2-barrier, counted vmcnt) — full-machine small GEMMs ============
// ADDI: add identity (C[row][col] += (col == row&1023)) for the Wcomb fold.
template <bool ADDI>
__global__ __launch_bounds__(256) void gemm128(const u16* __restrict__ A,
                                               const u16* __restrict__ Bt,
                                               u16* __restrict__ C,
                                               int N, int K, int lda) {
    __shared__ __align__(16) u16 lds[32768];   // 64 KB
    const int t = threadIdx.x;
    const int ntn = N >> 7;
    const int nwg = gridDim.x;                 // % 8 == 0
    int bid = (int)blockIdx.x;
    bid = (bid & 7) * (nwg >> 3) + (bid >> 3);
    const int tm = bid / ntn, tn = bid - tm * ntn;
    const size_t m0 = (size_t)tm << 7, n0 = (size_t)tn << 7;
    const int w = t >> 6, lane = t & 63;
    const int wr = w >> 1, wc = w & 1;

    const int r0 = t >> 3;                      // 0..31
    const int ksrc = (t & 7) ^ (r0 & 7);
    const u16* sA = A + (m0 + r0) * (size_t)lda + ksrc * 8;
    const u16* sB = Bt + (n0 + r0) * (size_t)K + ksrc * 8;
    const size_t stA = (size_t)32 * lda, stB = (size_t)32 * K;

    const int kx = lane & 7;
    const int ks0 = (((lane >> 4) ^ kx) << 3);
    const int ks1 = (((4 + (lane >> 4)) ^ kx) << 3);
    const int ao = ((wr << 6) | (lane & 15)) << 6;
    const int bo = 8192 + ((((wc << 6) | (lane & 15))) << 6);

    f32x4 acc[4][4];
#pragma unroll
    for (int i = 0; i < 4; i++)
#pragma unroll
        for (int j = 0; j < 4; j++)
#pragma unroll
            for (int r = 0; r < 4; r++) acc[i][j][r] = 0.0f;

#define STAGE128(bb, ko)                                                      \
    do {                                                                      \
        u16* dA_ = lds + (bb) * 16384 + (w << 9);                             \
        u16* dB_ = dA_ + 8192;                                                \
        _Pragma("unroll")                                                     \
        for (int j_ = 0; j_ < 4; j_++) {                                      \
            lds16(sA + (ko) + j_ * stA, dA_ + j_ * 2048);                     \
            lds16(sB + (ko) + j_ * stB, dB_ + j_ * 2048);                     \
        }                                                                     \
    } while (0)

    const int NT = K >> 6;
    STAGE128(0, 0);
    for (int kt = 0; kt < NT; kt++) {
        const int b = kt & 1;
        asm volatile("" ::: "memory");
        if (kt + 1 < NT) {
            STAGE128(b ^ 1, (size_t)(kt + 1) << 6);
            asm volatile("s_waitcnt vmcnt(8)" ::: "memory");
        } else {
            asm volatile("s_waitcnt vmcnt(0)" ::: "memory");
        }
        __builtin_amdgcn_s_barrier();
        asm volatile("" ::: "memory");
        const u16* Lb = lds + b * 16384;
#pragma unroll
        for (int kc = 0; kc < 2; kc++) {
            const int ksl = kc ? ks1 : ks0;
            bf16x8 af[4], bfr[4];
#pragma unroll
            for (int i = 0; i < 4; i++)
                af[i] = *reinterpret_cast<const bf16x8*>(Lb + ao + i * 1024 + ksl);
#pragma unroll
            for (int j = 0; j < 4; j++)
                bfr[j] = *reinterpret_cast<const bf16x8*>(Lb + bo + j * 1024 + ksl);
            __builtin_amdgcn_s_setprio(1);
#pragma unroll
            for (int i = 0; i < 4; i++)
#pragma unroll
                for (int j = 0; j < 4; j++)
                    acc[i][j] = __builtin_amdgcn_mfma_f32_16x16x32_bf16(af[i], bfr[j], acc[i][j], 0, 0, 0);
            __builtin_amdgcn_s_setprio(0);
        }
        asm volatile("" ::: "memory");
        __builtin_amdgcn_s_barrier();
    }
#undef STAGE128

    const int crow = (lane >> 4) << 2, ccol = lane & 15;
#pragma unroll
    for (int i = 0; i < 4; i++)
#pragma unroll
        for (int j = 0; j < 4; j++) {
            size_t row = m0 + (wr << 6) + (i << 4) + crow;
            size_t col = n0 + (wc << 6) + (j << 4) + ccol;
#pragma unroll
            for (int r = 0; r < 4; r++) {
                float v = acc[i][j][r];
                if (ADDI && col == ((row + r) & 1023)) v += 1.0f;
                C[(row + r) * (size_t)N + col] = f2bf(v);
            }
        }
}

// ===== KtV partials via Gram: part[split] += Wk[d][h64+i] * T_b[d][h64+j], d-split =====
// Verbatim R10 ktv_kernel structure (proven ~8 us at 2048 blocks): per (bh, split of 64 d),
// 64x64 fp32 outer-product accumulate. grid (64, 16) = 1024 blocks, high TLP.
__global__ __launch_bounds__(256) void ktv2_kernel(const u16* __restrict__ WkD,
                                                   const u16* __restrict__ Tm,
                                                   float* __restrict__ part) {
    const int bh = blockIdx.x, split = blockIdx.y;
    const int b = bh >> 4, h = bh & 15;
    const u16* Kp = WkD + h * 64;                              // [d][1024]
    const u16* Vp = Tm + (size_t)b * 1024 * 1024 + h * 64;     // [d][1024]
    __shared__ float ks[8][64], vs[8][64];
    float acc[16];
#pragma unroll
    for (int i = 0; i < 16; i++) acc[i] = 0.0f;
    const int t = threadIdx.x, r = t >> 4, c = t & 15;
    const int lr = t >> 5, lc = (t & 31) * 2;
    for (int l0 = split * 64; l0 < split * 64 + 64; l0 += 8) {
        unsigned kk = *(const unsigned*)(Kp + (size_t)(l0 + lr) * 1024 + lc);
        unsigned vv = *(const unsigned*)(Vp + (size_t)(l0 + lr) * 1024 + lc);
        ks[lr][lc] = bf2f((u16)kk); ks[lr][lc + 1] = bf2f((u16)(kk >> 16));
        vs[lr][lc] = bf2f((u16)vv); vs[lr][lc + 1] = bf2f((u16)(vv >> 16));
        __syncthreads();
#pragma unroll
        for (int i = 0; i < 8; i++) {
            float kvr[4], vw[4];
#pragma unroll
            for (int a = 0; a < 4; a++) { kvr[a] = ks[i][r + 16 * a]; vw[a] = vs[i][c + 16 * a]; }
#pragma unroll
            for (int a = 0; a < 4; a++)
#pragma unroll
                for (int q = 0; q < 4; q++) acc[a * 4 + q] += kvr[a] * vw[q];
        }
        __syncthreads();
    }
    float* o = part + ((size_t)split * 64 + bh) * 4096;
#pragma unroll
    for (int a = 0; a < 4; a++)
#pragma unroll
        for (int q = 0; q < 4; q++) o[(r + 16 * a) * 64 + (c + 16 * q)] = acc[a * 4 + q];
}

__global__ __launch_bounds__(256) void ktv_reduce(const float* __restrict__ part,
                                                  float* __restrict__ ktv) {
    int i = blockIdx.x * 256 + threadIdx.x;  // 64*4096 = 262144
    float s = 0.0f;
#pragma unroll
    for (int sp = 0; sp < 16; sp++) s += part[(size_t)sp * 262144 + i];
    ktv[i] = s;
}

// ===== W'^T_b[n][h*64+i] = sum_j (KtV_bh[i][j]/8) * Wo[h*64+j][n]  -> bf16 =====
// kt reads are wave-uniform GLOBAL addresses -> s_load (K$ path), dual-issues with VALU.
__global__ __launch_bounds__(256) void wprime_kernel(const float* __restrict__ ktv,
                                                     const float* __restrict__ Wo,
                                                     u16* __restrict__ wp) {
    const int n = blockIdx.x * 256 + threadIdx.x;   // blockIdx.x in [0,4)
    const int h = blockIdx.y, b = blockIdx.z;
    const float* kt = ktv + ((size_t)(b * 16 + h) << 12);
    float acc[64];
#pragma unroll
    for (int i = 0; i < 64; i++) acc[i] = 0.0f;
    for (int j = 0; j < 64; j++) {
        float w = Wo[(size_t)(h * 64 + j) * 1024 + n];
#pragma unroll
        for (int i = 0; i < 64; i++) acc[i] += kt[i * 64 + j] * w;
    }
    u16* o = wp + ((size_t)b << 20) + (size_t)n * 1024 + h * 64;
    u16 ob[64];
#pragma unroll
    for (int i = 0; i < 64; i++) ob[i] = f2bf(acc[i] * 0.125f);
#pragma unroll
    for (int i = 0; i < 8; i++)
        ((uint4*)o)[i] = ((const uint4*)ob)[i];
}

// ===== LN1: h1b = bf16(LN(xr)) — xr already holds x + attn_out (identity fold) =====
__global__ __launch_bounds__(256) void ln1_kernel(const u16* __restrict__ xr,
                                                  const float* __restrict__ g,
                                                  const float* __restrict__ be,
                                                  u16* __restrict__ outB) {
    __shared__ float sm[4];
    const int row = blockIdx.x, t = threadIdx.x;
    const ushort4 xv = ((const ushort4*)(xr + (size_t)row * 1024))[t];
    float x0 = bf2f(xv.x), x1 = bf2f(xv.y), x2 = bf2f(xv.z), x3 = bf2f(xv.w);
    float s = x0 + x1 + x2 + x3;
#pragma unroll
    for (int off = 32; off > 0; off >>= 1) s += __shfl_down(s, off);
    if ((t & 63) == 0) sm[t >> 6] = s;
    __syncthreads();
    const float mean = (sm[0] + sm[1] + sm[2] + sm[3]) * (1.0f / 1024.0f);
    __syncthreads();
    x0 -= mean; x1 -= mean; x2 -= mean; x3 -= mean;
    float s2 = x0 * x0 + x1 * x1 + x2 * x2 + x3 * x3;
#pragma unroll
    for (int off = 32; off > 0; off >>= 1) s2 += __shfl_down(s2, off);
    if ((t & 63) == 0) sm[t >> 6] = s2;
    __syncthreads();
    const float var = (sm[0] + sm[1] + sm[2] + sm[3]) * (1.0f / 1024.0f);
    const float rs = rsqrtf(var + 1e-5f);
    const float4 gv = ((const float4*)g)[t];
    const float4 bv = ((const float4*)be)[t];
    ushort4 ob;
    ob.x = f2bf(x0 * rs * gv.x + bv.x);
    ob.y = f2bf(x1 * rs * gv.y + bv.y);
    ob.z = f2bf(x2 * rs * gv.z + bv.z);
    ob.w = f2bf(x3 * rs * gv.w + bv.w);
    ((ushort4*)(outB + (size_t)row * 1024))[t] = ob;
}

// ===== LN2: out = f32(LN(ff_bf + h1_bf)) =====
__global__ __launch_bounds__(256) void ln2_kernel(const u16* __restrict__ ff,
                                                  const u16* __restrict__ h1,
                                                  const float* __restrict__ g,
                                                  const float* __restrict__ be,
                                                  float* __restrict__ outF) {
    __shared__ float sm[4];
    const int row = blockIdx.x, t = threadIdx.x;
    const ushort4 fv = ((const ushort4*)(ff + (size_t)row * 1024))[t];
    const ushort4 hv = ((const ushort4*)(h1 + (size_t)row * 1024))[t];
    float x0 = bf2f(fv.x) + bf2f(hv.x), x1 = bf2f(fv.y) + bf2f(hv.y);
    float x2 = bf2f(fv.z) + bf2f(hv.z), x3 = bf2f(fv.w) + bf2f(hv.w);
    float s = x0 + x1 + x2 + x3;
#pragma unroll
    for (int off = 32; off > 0; off >>= 1) s += __shfl_down(s, off);
    if ((t & 63) == 0) sm[t >> 6] = s;
    __syncthreads();
    const float mean = (sm[0] + sm[1] + sm[2] + sm[3]) * (1.0f / 1024.0f);
    __syncthreads();
    x0 -= mean; x1 -= mean; x2 -= mean; x3 -= mean;
    float s2 = x0 * x0 + x1 * x1 + x2 * x2 + x3 * x3;
#pragma unroll
    for (int off = 32; off > 0; off >>= 1) s2 += __shfl_down(s2, off);
    if ((t & 63) == 0) sm[t >> 6] = s2;
    __syncthreads();
    const float var = (sm[0] + sm[1] + sm[2] + sm[3]) * (1.0f / 1024.0f);
    const float rs = rsqrtf(var + 1e-5f);
    const float4 gv = ((const float4*)g)[t];
    const float4 bv = ((const float4*)be)[t];
    float4 o;
    o.x = x0 * rs * gv.x + bv.x;
    o.y = x1 * rs * gv.y + bv.y;
    o.z = x2 * rs * gv.z + bv.z;
    o.w = x3 * rs * gv.w + bv.w;
    ((float4*)(outF + (size_t)row * 1024))[t] = o;
}

extern "C" void kernel_launch(void* const* d_in, const int* in_sizes, int n_in,
                              void* d_out, int out_size, void* d_ws, size_t ws_size,
                              hipStream_t stream) {
    const float* seq = (const float*)d_in[0];
    const float* Wq  = (const float*)d_in[1];
    const float* Wk  = (const float*)d_in[2];
    const float* Wv  = (const float*)d_in[3];
    const float* Wo  = (const float*)d_in[4];
    const float* g1  = (const float*)d_in[5];
    const float* b1  = (const float*)d_in[6];
    const float* Wl  = (const float*)d_in[7];
    const float* bl  = (const float*)d_in[8];
    const float* g2  = (const float*)d_in[9];
    const float* b2  = (const float*)d_in[10];

    char* ws = (char*)d_ws;
    const size_t MB = 1024 * 1024;
    u16*   x_bf    = (u16*)(ws + 0);            // 16 MB [8192][1024]
    u16*   wt      = (u16*)(ws + 16 * MB);      // 10 MB: [Wq, Wk^T, Wv^T, Wl, Wk] bf16
    u16*   xT      = (u16*)(ws + 26 * MB);      // 16 MB [1024][8192] (x transposed)
    u16*   G       = (u16*)(ws + 42 * MB);      // 8 MB  [4][1024][1024] Gram per batch
    u16*   Tm      = (u16*)(ws + 50 * MB);      // 8 MB  [4096][1024] T = G @ Wv
    float* kpart   = (float*)(ws + 58 * MB);    // 16 MB [16][64][4096]
    float* ktv     = (float*)(ws + 74 * MB);    // 1 MB  [64][64][64]
    u16*   wpr     = (u16*)(ws + 75 * MB);      // 8 MB  [4][1024][1024] W'^T per batch
    u16*   wcomb   = (u16*)(ws + 83 * MB);      // 8 MB  [4][1024][1024] (I + Wcomb)^T per batch
    u16*   attnres = (u16*)(ws + 91 * MB);      // 16 MB — holds x + attn_out
    u16*   h1b     = (u16*)(ws + 107 * MB);     // 16 MB
    u16*   ffb     = (u16*)(ws + 123 * MB);     // 16 MB

    // 1. x_bf + xT = bf16(seq + positional); weights -> bf16 (incl. direct Wk)  (merged)
    prep_all<<<dim3(4096 + 5120), dim3(256), 0, stream>>>(seq, Wq, Wk, Wv, Wl,
                                                          x_bf, xT, wt);
    // 2. G_b = X_b^T X_b  (K=2048; grid 4 batches x 64 tiles = 256)
    gram_kernel<<<dim3(256), dim3(256), 0, stream>>>(xT, G);
    // 3. T = G_stack @ Wv  ([4096,1024] @ [1024,1024]; grid 32x8 = 256)
    gemm128<false><<<dim3(256), dim3(256), 0, stream>>>(G, wt + (size_t)2 * MB, Tm,
                                                        1024, 1024, 1024);
    // 4. KtV partials: part[split] = Wk[dsplit]^T T_b[dsplit,h]  (grid 64 x 16, high TLP)
    ktv2_kernel<<<dim3(64, 16), dim3(256), 0, stream>>>(wt + (size_t)4 * MB, Tm, kpart);
    // 5. deterministic reduce -> ktv (f32)
    ktv_reduce<<<dim3(1024), dim3(256), 0, stream>>>(kpart, ktv);
    // 6. W'^T_b = (blockdiag(KtV_b)/8 @ Wo)^T -> bf16  (kt via scalar-load path)
    wprime_kernel<<<dim3(4, 16, 4), dim3(256), 0, stream>>>(ktv, Wo, wpr);
    // 7. (I + Wcomb)^T_b = W'^T_b @ Wq^T + I  (grid 32x8 = 256)
    gemm128<true><<<dim3(256), dim3(256), 0, stream>>>(wpr, wt, wcomb, 1024, 1024, 1024);
    // 8. attnres = x @ (I + Wcomb_b) = x + attn_out  (B batched per 2048 rows; grid 256)
    gemm8p<2><<<dim3(256), dim3(512), 0, stream>>>(x_bf, wcomb, attnres, nullptr,
                                                   1024, 1024, 1024, (size_t)1024 * 1024);
    // 9. h1b = bf16(LN(attnres))
    ln1_kernel<<<dim3(8192), dim3(256), 0, stream>>>(attnres, g1, b1, h1b);
    // 10. ff = relu(h1 @ Wl^T + bl) -> bf16  (grid 256)
    gemm8p<3><<<dim3(256), dim3(512), 0, stream>>>(h1b, wt + (size_t)3 * MB, ffb,
                                                   bl, 1024, 1024, 1024, 0);
    // 11. out = LN(ff + h1)
    ln2_kernel<<<dim3(8192), dim3(256), 0, stream>>>(ffb, h1b, g2, b2, (float*)d_out);
}

// Round 13
// 180.869 us; speedup vs baseline: 1.2455x; 1.0308x over previous
//
#include <hip/hip_runtime.h>
#include <cstdint>

typedef unsigned short u16;
typedef __bf16 bf16x8 __attribute__((ext_vector_type(8)));
typedef float f32x4 __attribute__((ext_vector_type(4)));

// ---------- bf16 helpers (RNE) ----------
__device__ __forceinline__ u16 f2bf(float f) {
    unsigned u = __float_as_uint(f);
    u += 0x7fffu + ((u >> 16) & 1u);
    return (u16)(u >> 16);
}
__device__ __forceinline__ float bf2f(u16 h) {
    return __uint_as_float(((unsigned)h) << 16);
}

// ---------- async global->LDS (16B per lane, wave-uniform LDS base) ----------
__device__ __forceinline__ void lds16(const void* g, void* l) {
    __builtin_amdgcn_global_load_lds(
        (const __attribute__((address_space(1))) void*)g,
        (__attribute__((address_space(3))) void*)l, 16, 0, 0);
}

// ---------- positional encoding term for element e of row l ----------
__device__ __forceinline__ float pos_term(int l, int e) {
    const float c = -13.287712379549449f / 512.0f;       // -log2(10000)/512
    int ii = e & 511;
    float st  = exp2f(c * (float)ii);
    float arg = (float)l * st;
    return (e < 512) ? sinf(arg) : cosf(arg);
}

// ========== merged prep ==========
// blocks [0,4096):        x 64x32 tiles -> x_bf (row-major) AND xT ([1024][8192])
// blocks [4096,4096+4096): weights -> bf16: mat0=Wq, mat1=Wv^T, mat2=Wl, mat3=Wk
__global__ __launch_bounds__(256) void prep_all(const float* __restrict__ seq,
                                                const float* __restrict__ wq,
                                                const float* __restrict__ wk,
                                                const float* __restrict__ wv,
                                                const float* __restrict__ wl,
                                                u16* __restrict__ xb,
                                                u16* __restrict__ xt,
                                                u16* __restrict__ wt) {
    const int bx = blockIdx.x;
    const int t = threadIdx.x;
    if (bx < 4096) {
        __shared__ u16 tb[64][33];
        const int rt = bx >> 5, ct = bx & 31;            // 128 row-tiles x 32 col-tiles
        const int r0 = rt * 64, c0 = ct * 32;
        const int r_l = t >> 2, c8 = (t & 3) * 8;        // load: 64 rows x 4 col-chunks
        const int row = r0 + r_l, l = row & 2047;
        const float* sp = seq + (size_t)row * 1024 + c0 + c8;
        float4 a0 = ((const float4*)sp)[0];
        float4 a1 = ((const float4*)sp)[1];
        float v[8] = {a0.x, a0.y, a0.z, a0.w, a1.x, a1.y, a1.z, a1.w};
        u16 ob[8];
#pragma unroll
        for (int jj = 0; jj < 8; jj++) {
            v[jj] += pos_term(l, c0 + c8 + jj);
            ob[jj] = f2bf(v[jj]);
            tb[r_l][c8 + jj] = ob[jj];
        }
        u16* xp = xb + (size_t)row * 1024 + c0 + c8;
        ((ushort4*)xp)[0] = *(const ushort4*)&ob[0];
        ((ushort4*)xp)[1] = *(const ushort4*)&ob[4];
        __syncthreads();
        const int c_l = t >> 3, r8 = (t & 7) * 8;        // store: 32 cols x 8 row-chunks
        u16 tv[8];
#pragma unroll
        for (int jj = 0; jj < 8; jj++) tv[jj] = tb[r8 + jj][c_l];
        u16* tp = xt + (size_t)(c0 + c_l) * 8192 + r0 + r8;
        ((ushort4*)tp)[0] = *(const ushort4*)&tv[0];
        ((ushort4*)tp)[1] = *(const ushort4*)&tv[4];
        return;
    }
    const int idx = bx - 4096;               // [0, 4096)
    const int mat = idx >> 10, bxw = idx & 1023;
    const int gx = bxw & 31, gy = bxw >> 5;
    const int tx = t & 31, ty = t >> 5;
    // mat0 = Wq direct, mat1 = Wv^T, mat2 = Wl direct, mat3 = Wk direct
    const float* src = (mat == 0) ? wq : (mat == 1) ? wv : (mat == 2) ? wl : wk;
    u16* dst = wt + (size_t)mat * 1024 * 1024;
    if (mat != 1) {
        int col = gx * 32 + tx, row0 = gy * 32;
#pragma unroll
        for (int j = 0; j < 32; j += 8)
            dst[(size_t)(row0 + ty + j) * 1024 + col] = f2bf(src[(size_t)(row0 + ty + j) * 1024 + col]);
    } else {
        __shared__ float tile[32][33];
        int col = gx * 32 + tx, row0 = gy * 32;
#pragma unroll
        for (int j = 0; j < 32; j += 8)
            tile[ty + j][tx] = src[(size_t)(row0 + ty + j) * 1024 + col];
        __syncthreads();
        int col2 = gy * 32 + tx, row20 = gx * 32;
#pragma unroll
        for (int j = 0; j < 32; j += 8)
            dst[(size_t)(row20 + ty + j) * 1024 + col2] = f2bf(tile[tx][ty + j]);
    }
}

// ======== 128x128 bf16 GEMM, 8 waves (2M x 4N, per-wave 64x32) — 2/SIMD TLP ========
// C = A @ Bt^T (+ optional I). Batched: if tilesPB>0, batch bt = bid/tilesPB with
// A += bt*aBatch, Bt += bt*bBatch, C += bt*cBatch; tile index within batch = bid%tilesPB,
// decomposed tm = tl/ntn, tn = tl%ntn. Same swizzle + 2-barrier counted-vmcnt race
// structure as gemm8p (0 bank conflicts R3-R12). 4 lds16/thread/tile -> vmcnt(4).
template <bool ADDI>
__global__ __launch_bounds__(512) void gemm128w8(const u16* __restrict__ A,
                                                 const u16* __restrict__ Bt,
                                                 u16* __restrict__ C,
                                                 int N, int K, int lda, int ntn,
                                                 int tilesPB, size_t aBatch,
                                                 size_t bBatch, size_t cBatch) {
    __shared__ __align__(16) u16 lds[32768];   // 64 KB = 2 buf x (A 16KB + B 16KB)
    const int t = threadIdx.x;
    const int nwg = gridDim.x;                 // % 8 == 0
    int bid = (int)blockIdx.x;
    bid = (bid & 7) * (nwg >> 3) + (bid >> 3); // bijective XCD swizzle
    int bt = 0, tl = bid;
    if (tilesPB > 0) { bt = bid / tilesPB; tl = bid - bt * tilesPB; }
    const int tm = tl / ntn, tn = tl - tm * ntn;
    const size_t m0 = (size_t)tm << 7, n0 = (size_t)tn << 7;
    const u16* Ae = A + (size_t)bt * aBatch;
    const u16* Be = Bt + (size_t)bt * bBatch;
    u16* Ce = C + (size_t)bt * cBatch;
    const int w = t >> 6, lane = t & 63;
    const int wr = w >> 2, wc = w & 3;         // 2 (M) x 4 (N); per-wave 64x32

    const int r0 = t >> 3;                      // 0..63
    const int ksrc = (t & 7) ^ (r0 & 7);
    const u16* sA0 = Ae + (m0 + r0) * (size_t)lda + ksrc * 8;
    const u16* sA1 = sA0 + (size_t)64 * lda;
    const u16* sB0 = Be + (n0 + r0) * (size_t)lda + ksrc * 8;
    const u16* sB1 = sB0 + (size_t)64 * lda;

    const int kx = lane & 7;
    const int ks0 = (((lane >> 4) ^ kx) << 3);
    const int ks1 = (((4 + (lane >> 4)) ^ kx) << 3);
    const int ao = ((wr << 6) | (lane & 15)) << 6;            // A row*64
    const int bo = 8192 + (((wc << 5) | (lane & 15)) << 6);   // B region + row*64

    f32x4 acc[4][2];
#pragma unroll
    for (int i = 0; i < 4; i++)
#pragma unroll
        for (int j = 0; j < 2; j++)
#pragma unroll
            for (int r = 0; r < 4; r++) acc[i][j][r] = 0.0f;

#define STAGEW8(bb, ko)                                                       \
    do {                                                                      \
        u16* d_ = lds + (bb) * 16384 + (w << 9);                              \
        lds16(sA0 + (ko), d_);                                                \
        lds16(sA1 + (ko), d_ + 4096);                                         \
        lds16(sB0 + (ko), d_ + 8192);                                         \
        lds16(sB1 + (ko), d_ + 12288);                                        \
    } while (0)

    const int NT = K >> 6;
    STAGEW8(0, 0);
    for (int kt = 0; kt < NT; kt++) {
        const int b = kt & 1;
        asm volatile("" ::: "memory");
        if (kt + 1 < NT) {
            STAGEW8(b ^ 1, (size_t)(kt + 1) << 6);
            asm volatile("s_waitcnt vmcnt(4)" ::: "memory");  // tile-t retired; prefetch in flight
        } else {
            asm volatile("s_waitcnt vmcnt(0)" ::: "memory");
        }
        __builtin_amdgcn_s_barrier();
        asm volatile("" ::: "memory");
        const u16* Lb = lds + b * 16384;
#pragma unroll
        for (int kc = 0; kc < 2; kc++) {
            const int ksl = kc ? ks1 : ks0;
            bf16x8 af[4], bfr[2];
#pragma unroll
            for (int i = 0; i < 4; i++)
                af[i] = *reinterpret_cast<const bf16x8*>(Lb + ao + i * 1024 + ksl);
#pragma unroll
            for (int j = 0; j < 2; j++)
                bfr[j] = *reinterpret_cast<const bf16x8*>(Lb + bo + j * 1024 + ksl);
            __builtin_amdgcn_s_setprio(1);
#pragma unroll
            for (int i = 0; i < 4; i++)
#pragma unroll
                for (int j = 0; j < 2; j++)
                    acc[i][j] = __builtin_amdgcn_mfma_f32_16x16x32_bf16(af[i], bfr[j], acc[i][j], 0, 0, 0);
            __builtin_amdgcn_s_setprio(0);
        }
        asm volatile("" ::: "memory");
        __builtin_amdgcn_s_barrier();
    }
#undef STAGEW8

    const int crow = (lane >> 4) << 2, ccol = lane & 15;
#pragma unroll
    for (int i = 0; i < 4; i++)
#pragma unroll
        for (int j = 0; j < 2; j++) {
            size_t row = m0 + (wr << 6) + (i << 4) + crow;
            size_t col = n0 + (wc << 5) + (j << 4) + ccol;
#pragma unroll
            for (int r = 0; r < 4; r++) {
                float v = acc[i][j][r];
                size_t grow = row + r + (size_t)bt * 0;   // row within batch view
                if (ADDI && col == ((row + r) & 1023)) v += 1.0f;
                Ce[(row + r) * (size_t)N + col] = f2bf(v);
                (void)grow;
            }
        }
}

// ============ 128x256 bf16 GEMM (2-barrier, counted vmcnt) — proven structure ============
// EPI: 2 = bf16 out, 3 = bf16 bias+relu out.
// bstride: if nonzero, Bt batched per 2048 A-rows.
template <int EPI>
__global__ __launch_bounds__(512) void gemm8p(const u16* __restrict__ A,
                                              const u16* __restrict__ Bt,
                                              void* __restrict__ Cv,
                                              const float* __restrict__ bias,
                                              int N, int K, int lda, size_t bstride) {
    __shared__ __align__(16) u16 lds[49152];   // 96 KB
    const int t = threadIdx.x;
    const int ntn = N >> 8;
    const int nwg = gridDim.x;                 // % 8 == 0
    int bid = (int)blockIdx.x;
    bid = (bid & 7) * (nwg >> 3) + (bid >> 3);
    const int tm = bid / ntn, tn = bid - tm * ntn;
    const size_t m0 = (size_t)tm << 7, n0 = (size_t)tn << 8;
    const int w = t >> 6, lane = t & 63;
    const int wr = w >> 2, wc = w & 3;
    const u16* Bt_e = Bt + (bstride ? (m0 >> 11) * bstride : 0);

    const int r0 = t >> 3;
    const int ksrc = (t & 7) ^ (r0 & 7);
    const u16* sA0 = A + (m0 + r0) * (size_t)lda + ksrc * 8;
    const u16* sA1 = sA0 + (size_t)64 * lda;
    const u16* sB0 = Bt_e + (n0 + r0) * (size_t)K + ksrc * 8;
    const u16* sB1 = sB0 + (size_t)64 * K;
    const u16* sB2 = sB0 + (size_t)128 * K;
    const u16* sB3 = sB0 + (size_t)192 * K;
    u16* dstW = lds + (w << 9);

    const int ao = ((wr << 6) | (lane & 15)) << 6;
    const int bo = 8192 + ((((wc << 6) | (lane & 15))) << 6);
    const int kx = lane & 7;
    const int ks0 = (((lane >> 4) ^ kx) << 3);
    const int ks1 = (((4 + (lane >> 4)) ^ kx) << 3);

    f32x4 acc[4][4];
#pragma unroll
    for (int i = 0; i < 4; i++)
#pragma unroll
        for (int j = 0; j < 4; j++)
#pragma unroll
            for (int r = 0; r < 4; r++) acc[i][j][r] = 0.0f;

    const int NT = K >> 6;
    lds16(sA0, dstW);          lds16(sA1, dstW + 4096);
    lds16(sB0, dstW + 8192);   lds16(sB1, dstW + 12288);
    lds16(sB2, dstW + 16384);  lds16(sB3, dstW + 20480);

    for (int kt = 0; kt < NT; kt++) {
        const int b = kt & 1;
        asm volatile("" ::: "memory");
        if (kt + 1 < NT) {
            const size_t ko = (size_t)(kt + 1) << 6;
            u16* d = dstW + (b ^ 1) * 24576;
            lds16(sA0 + ko, d);          lds16(sA1 + ko, d + 4096);
            lds16(sB0 + ko, d + 8192);   lds16(sB1 + ko, d + 12288);
            lds16(sB2 + ko, d + 16384);  lds16(sB3 + ko, d + 20480);
            asm volatile("s_waitcnt vmcnt(6)" ::: "memory");
        } else {
            asm volatile("s_waitcnt vmcnt(0)" ::: "memory");
        }
        __builtin_amdgcn_s_barrier();
        asm volatile("" ::: "memory");
        const u16* Lb = lds + b * 24576;
#pragma unroll
        for (int kc = 0; kc < 2; kc++) {
            const int ksl = kc ? ks1 : ks0;
            bf16x8 af[4], bfr[4];
#pragma unroll
            for (int i = 0; i < 4; i++)
                af[i] = *reinterpret_cast<const bf16x8*>(Lb + ao + i * 1024 + ksl);
#pragma unroll
            for (int j = 0; j < 4; j++)
                bfr[j] = *reinterpret_cast<const bf16x8*>(Lb + bo + j * 1024 + ksl);
            __builtin_amdgcn_s_setprio(1);
#pragma unroll
            for (int i = 0; i < 4; i++)
#pragma unroll
                for (int j = 0; j < 4; j++)
                    acc[i][j] = __builtin_amdgcn_mfma_f32_16x16x32_bf16(af[i], bfr[j], acc[i][j], 0, 0, 0);
            __builtin_amdgcn_s_setprio(0);
        }
        asm volatile("" ::: "memory");
        __builtin_amdgcn_s_barrier();
    }

    const int crow = (lane >> 4) << 2, ccol = lane & 15;
#pragma unroll
    for (int i = 0; i < 4; i++)
#pragma unroll
        for (int j = 0; j < 4; j++) {
            size_t row = m0 + (wr << 6) + (i << 4) + crow;
            size_t col = n0 + (wc << 6) + (j << 4) + ccol;
#pragma unroll
            for (int r = 0; r < 4; r++) {
                float v = acc[i][j][r];
                if (EPI == 3) { v += bias[col]; v = fmaxf(v, 0.0f); }
                ((u16*)Cv)[(row + r) * (size_t)N + col] = f2bf(v);
            }
        }
}

// ===== KtV partials via Gram: part[split] += Wk[d][h64+i] * T_b[d][h64+j], d-split =====
// Proven R10 structure: per (bh, split of 64 d), 64x64 fp32 outer-product accumulate.
// grid (64, 16) = 1024 blocks, high TLP.
__global__ __launch_bounds__(256) void ktv2_kernel(const u16* __restrict__ WkD,
                                                   const u16* __restrict__ Tm,
                                                   float* __restrict__ part) {
    const int bh = blockIdx.x, split = blockIdx.y;
    const int b = bh >> 4, h = bh & 15;
    const u16* Kp = WkD + h * 64;                              // [d][1024]
    const u16* Vp = Tm + (size_t)b * 1024 * 1024 + h * 64;     // [d][1024]
    __shared__ float ks[8][64], vs[8][64];
    float acc[16];
#pragma unroll
    for (int i = 0; i < 16; i++) acc[i] = 0.0f;
    const int t = threadIdx.x, r = t >> 4, c = t & 15;
    const int lr = t >> 5, lc = (t & 31) * 2;
    for (int l0 = split * 64; l0 < split * 64 + 64; l0 += 8) {
        unsigned kk = *(const unsigned*)(Kp + (size_t)(l0 + lr) * 1024 + lc);
        unsigned vv = *(const unsigned*)(Vp + (size_t)(l0 + lr) * 1024 + lc);
        ks[lr][lc] = bf2f((u16)kk); ks[lr][lc + 1] = bf2f((u16)(kk >> 16));
        vs[lr][lc] = bf2f((u16)vv); vs[lr][lc + 1] = bf2f((u16)(vv >> 16));
        __syncthreads();
#pragma unroll
        for (int i = 0; i < 8; i++) {
            float kvr[4], vw[4];
#pragma unroll
            for (int a = 0; a < 4; a++) { kvr[a] = ks[i][r + 16 * a]; vw[a] = vs[i][c + 16 * a]; }
#pragma unroll
            for (int a = 0; a < 4; a++)
#pragma unroll
                for (int q = 0; q < 4; q++) acc[a * 4 + q] += kvr[a] * vw[q];
        }
        __syncthreads();
    }
    float* o = part + ((size_t)split * 64 + bh) * 4096;
#pragma unroll
    for (int a = 0; a < 4; a++)
#pragma unroll
        for (int q = 0; q < 4; q++) o[(r + 16 * a) * 64 + (c + 16 * q)] = acc[a * 4 + q];
}

__global__ __launch_bounds__(256) void ktv_reduce(const float* __restrict__ part,
                                                  float* __restrict__ ktv) {
    int i = blockIdx.x * 256 + threadIdx.x;  // 64*4096 = 262144
    float s = 0.0f;
#pragma unroll
    for (int sp = 0; sp < 16; sp++) s += part[(size_t)sp * 262144 + i];
    ktv[i] = s;
}

// ===== W'^T_b[n][h*64+i] = sum_j (KtV_bh[i][j]/8) * Wo[h*64+j][n]  -> bf16 =====
// kt reads are wave-uniform GLOBAL addresses -> s_load (K$ path), dual-issues with VALU.
__global__ __launch_bounds__(256) void wprime_kernel(const float* __restrict__ ktv,
                                                     const float* __restrict__ Wo,
                                                     u16* __restrict__ wp) {
    const int n = blockIdx.x * 256 + threadIdx.x;   // blockIdx.x in [0,4)
    const int h = blockIdx.y, b = blockIdx.z;
    const float* kt = ktv + ((size_t)(b * 16 + h) << 12);
    float acc[64];
#pragma unroll
    for (int i = 0; i < 64; i++) acc[i] = 0.0f;
    for (int j = 0; j < 64; j++) {
        float w = Wo[(size_t)(h * 64 + j) * 1024 + n];
#pragma unroll
        for (int i = 0; i < 64; i++) acc[i] += kt[i * 64 + j] * w;
    }
    u16* o = wp + ((size_t)b << 20) + (size_t)n * 1024 + h * 64;
    u16 ob[64];
#pragma unroll
    for (int i = 0; i < 64; i++) ob[i] = f2bf(acc[i] * 0.125f);
#pragma unroll
    for (int i = 0; i < 8; i++)
        ((uint4*)o)[i] = ((const uint4*)ob)[i];
}

// ===== LN1: h1b = bf16(LN(xr)) — xr already holds x + attn_out (identity fold) =====
__global__ __launch_bounds__(256) void ln1_kernel(const u16* __restrict__ xr,
                                                  const float* __restrict__ g,
                                                  const float* __restrict__ be,
                                                  u16* __restrict__ outB) {
    __shared__ float sm[4];
    const int row = blockIdx.x, t = threadIdx.x;
    const ushort4 xv = ((const ushort4*)(xr + (size_t)row * 1024))[t];
    float x0 = bf2f(xv.x), x1 = bf2f(xv.y), x2 = bf2f(xv.z), x3 = bf2f(xv.w);
    float s = x0 + x1 + x2 + x3;
#pragma unroll
    for (int off = 32; off > 0; off >>= 1) s += __shfl_down(s, off);
    if ((t & 63) == 0) sm[t >> 6] = s;
    __syncthreads();
    const float mean = (sm[0] + sm[1] + sm[2] + sm[3]) * (1.0f / 1024.0f);
    __syncthreads();
    x0 -= mean; x1 -= mean; x2 -= mean; x3 -= mean;
    float s2 = x0 * x0 + x1 * x1 + x2 * x2 + x3 * x3;
#pragma unroll
    for (int off = 32; off > 0; off >>= 1) s2 += __shfl_down(s2, off);
    if ((t & 63) == 0) sm[t >> 6] = s2;
    __syncthreads();
    const float var = (sm[0] + sm[1] + sm[2] + sm[3]) * (1.0f / 1024.0f);
    const float rs = rsqrtf(var + 1e-5f);
    const float4 gv = ((const float4*)g)[t];
    const float4 bv = ((const float4*)be)[t];
    ushort4 ob;
    ob.x = f2bf(x0 * rs * gv.x + bv.x);
    ob.y = f2bf(x1 * rs * gv.y + bv.y);
    ob.z = f2bf(x2 * rs * gv.z + bv.z);
    ob.w = f2bf(x3 * rs * gv.w + bv.w);
    ((ushort4*)(outB + (size_t)row * 1024))[t] = ob;
}

// ===== LN2: out = f32(LN(ff_bf + h1_bf)) =====
__global__ __launch_bounds__(256) void ln2_kernel(const u16* __restrict__ ff,
                                                  const u16* __restrict__ h1,
                                                  const float* __restrict__ g,
                                                  const float* __restrict__ be,
                                                  float* __restrict__ outF) {
    __shared__ float sm[4];
    const int row = blockIdx.x, t = threadIdx.x;
    const ushort4 fv = ((const ushort4*)(ff + (size_t)row * 1024))[t];
    const ushort4 hv = ((const ushort4*)(h1 + (size_t)row * 1024))[t];
    float x0 = bf2f(fv.x) + bf2f(hv.x), x1 = bf2f(fv.y) + bf2f(hv.y);
    float x2 = bf2f(fv.z) + bf2f(hv.z), x3 = bf2f(fv.w) + bf2f(hv.w);
    float s = x0 + x1 + x2 + x3;
#pragma unroll
    for (int off = 32; off > 0; off >>= 1) s += __shfl_down(s, off);
    if ((t & 63) == 0) sm[t >> 6] = s;
    __syncthreads();
    const float mean = (sm[0] + sm[1] + sm[2] + sm[3]) * (1.0f / 1024.0f);
    __syncthreads();
    x0 -= mean; x1 -= mean; x2 -= mean; x3 -= mean;
    float s2 = x0 * x0 + x1 * x1 + x2 * x2 + x3 * x3;
#pragma unroll
    for (int off = 32; off > 0; off >>= 1) s2 += __shfl_down(s2, off);
    if ((t & 63) == 0) sm[t >> 6] = s2;
    __syncthreads();
    const float var = (sm[0] + sm[1] + sm[2] + sm[3]) * (1.0f / 1024.0f);
    const float rs = rsqrtf(var + 1e-5f);
    const float4 gv = ((const float4*)g)[t];
    const float4 bv = ((const float4*)be)[t];
    float4 o;
    o.x = x0 * rs * gv.x + bv.x;
    o.y = x1 * rs * gv.y + bv.y;
    o.z = x2 * rs * gv.z + bv.z;
    o.w = x3 * rs * gv.w + bv.w;
    ((float4*)(outF + (size_t)row * 1024))[t] = o;
}

extern "C" void kernel_launch(void* const* d_in, const int* in_sizes, int n_in,
                              void* d_out, int out_size, void* d_ws, size_t ws_size,
                              hipStream_t stream) {
    const float* seq = (const float*)d_in[0];
    const float* Wq  = (const float*)d_in[1];
    const float* Wk  = (const float*)d_in[2];
    const float* Wv  = (const float*)d_in[3];
    const float* Wo  = (const float*)d_in[4];
    const float* g1  = (const float*)d_in[5];
    const float* b1  = (const float*)d_in[6];
    const float* Wl  = (const float*)d_in[7];
    const float* bl  = (const float*)d_in[8];
    const float* g2  = (const float*)d_in[9];
    const float* b2  = (const float*)d_in[10];

    char* ws = (char*)d_ws;
    const size_t MB = 1024 * 1024;
    u16*   x_bf    = (u16*)(ws + 0);            // 16 MB [8192][1024]
    u16*   wt      = (u16*)(ws + 16 * MB);      // 8 MB: [Wq, Wv^T, Wl, Wk] bf16
    u16*   xT      = (u16*)(ws + 24 * MB);      // 16 MB [1024][8192] (x transposed)
    u16*   G       = (u16*)(ws + 40 * MB);      // 8 MB  [4][1024][1024] Gram per batch
    u16*   Tm      = (u16*)(ws + 48 * MB);      // 8 MB  [4096][1024] T = G @ Wv
    float* kpart   = (float*)(ws + 56 * MB);    // 16 MB [16][64][4096]
    float* ktv     = (float*)(ws + 72 * MB);    // 1 MB  [64][64][64]
    u16*   wpr     = (u16*)(ws + 73 * MB);      // 8 MB  [4][1024][1024] W'^T per batch
    u16*   wcomb   = (u16*)(ws + 81 * MB);      // 8 MB  [4][1024][1024] (I + Wcomb)^T per batch
    u16*   attnres = (u16*)(ws + 89 * MB);      // 16 MB — holds x + attn_out
    u16*   h1b     = (u16*)(ws + 105 * MB);     // 16 MB
    u16*   ffb     = (u16*)(ws + 121 * MB);     // 16 MB

    // 1. x_bf + xT = bf16(seq + positional); weights -> bf16  (merged)
    prep_all<<<dim3(4096 + 4096), dim3(256), 0, stream>>>(seq, Wq, Wk, Wv, Wl,
                                                          x_bf, xT, wt);
    // 2. G_b = X_b^T X_b  (K=2048; 4 batches x 64 tiles = 256 blocks, 8 waves)
    gemm128w8<false><<<dim3(256), dim3(512), 0, stream>>>(xT, xT, G,
                                                          1024, 2048, 8192, 8,
                                                          64, 2048, 2048, (size_t)1 << 20);
    // 3. T = G_stack @ Wv  ([4096,1024] @ [1024,1024]; 256 blocks, 8 waves)
    gemm128w8<false><<<dim3(256), dim3(512), 0, stream>>>(G, wt + (size_t)1 * MB, Tm,
                                                          1024, 1024, 1024, 8,
                                                          0, 0, 0, 0);
    // 4. KtV partials: part[split] = Wk[dsplit]^T T_b[dsplit,h]  (grid 64 x 16, high TLP)
    ktv2_kernel<<<dim3(64, 16), dim3(256), 0, stream>>>(wt + (size_t)3 * MB, Tm, kpart);
    // 5. deterministic reduce -> ktv (f32)
    ktv_reduce<<<dim3(1024), dim3(256), 0, stream>>>(kpart, ktv);
    // 6. W'^T_b = (blockdiag(KtV_b)/8 @ Wo)^T -> bf16  (kt via scalar-load path)
    wprime_kernel<<<dim3(4, 16, 4), dim3(256), 0, stream>>>(ktv, Wo, wpr);
    // 7. (I + Wcomb)^T_b = W'^T_b @ Wq^T + I  (256 blocks, 8 waves)
    gemm128w8<true><<<dim3(256), dim3(512), 0, stream>>>(wpr, wt, wcomb,
                                                         1024, 1024, 1024, 8,
                                                         0, 0, 0, 0);
    // 8. attnres = x @ (I + Wcomb_b) = x + attn_out  (B batched per 2048 rows; grid 256)
    gemm8p<2><<<dim3(256), dim3(512), 0, stream>>>(x_bf, wcomb, attnres, nullptr,
                                                   1024, 1024, 1024, (size_t)1024 * 1024);
    // 9. h1b = bf16(LN(attnres))
    ln1_kernel<<<dim3(8192), dim3(256), 0, stream>>>(attnres, g1, b1, h1b);
    // 10. ff = relu(h1 @ Wl^T + bl) -> bf16  (grid 256)
    gemm8p<3><<<dim3(256), dim3(512), 0, stream>>>(h1b, wt + (size_t)2 * MB, ffb,
                                                   bl, 1024, 1024, 1024, 0);
    // 11. out = LN(ff + h1)
    ln2_kernel<<<dim3(8192), dim3(256), 0, stream>>>(ffb, h1b, g2, b2, (float*)d_out);
}